// Round 2
// baseline (48573.276 us; speedup 1.0000x reference)
//
#include <hip/hip_runtime.h>

#define NTHREADS 1024
#define NB 256
#define TT 64
#define NV 19

// LDS layout (floats, all 16B-aligned offsets):
//  Sm:364  h0:2432  h1:2432  cur:1904  xs:4864  m1:4864  m2:4864  gb:4864  cb:2432  = 29020 floats = 116KB
// NOTE: xs, m1, m2 MUST stay contiguous (gemm_cols indexes mat = xs + kp*4864).

// ---- diffusion build: dst[n][0:256) = S @ src   (or 2*(S@src) - sub if sub != null)
// 16 waves: wave w owns rows {w, w+16}; 64 lanes cover the 256-float row as float4
__device__ __forceinline__ void diffuse(const float* Sm, const float* src, float* dst,
                                        const float* sub, int tid)
{
    const int w = tid >> 6;
    const int c4 = (tid & 63) << 2;
    const int n0 = w, n1 = w + 16;
    float4 a0 = {0.f, 0.f, 0.f, 0.f};
    float4 a1 = {0.f, 0.f, 0.f, 0.f};
#pragma unroll 1
    for (int m = 0; m < 19; ++m) {
        const float4 x4 = *(const float4*)(src + (m << 8) + c4);
        const float s0 = Sm[n0 * 19 + m];
        a0.x += s0 * x4.x; a0.y += s0 * x4.y; a0.z += s0 * x4.z; a0.w += s0 * x4.w;
        if (n1 < 19) {
            const float s1 = Sm[n1 * 19 + m];
            a1.x += s1 * x4.x; a1.y += s1 * x4.y; a1.z += s1 * x4.z; a1.w += s1 * x4.w;
        }
    }
    if (sub) {
        const float4 u0 = *(const float4*)(sub + (n0 << 8) + c4);
        a0.x = 2.f * a0.x - u0.x; a0.y = 2.f * a0.y - u0.y;
        a0.z = 2.f * a0.z - u0.z; a0.w = 2.f * a0.w - u0.w;
        if (n1 < 19) {
            const float4 u1 = *(const float4*)(sub + (n1 << 8) + c4);
            a1.x = 2.f * a1.x - u1.x; a1.y = 2.f * a1.y - u1.y;
            a1.z = 2.f * a1.z - u1.z; a1.w = 2.f * a1.w - u1.w;
        }
    }
    *(float4*)(dst + (n0 << 8) + c4) = a0;
    if (n1 < 19) *(float4*)(dst + (n1 << 8) + c4) = a1;
}

// ---- out(19 x J) += [k-interleaved stack of xs,m1,m2](19 x 3D) @ W(3D x J)
// Column-pair ownership: thread owns columns (j, j+1) for all 19 rows.
//  - acc[19][2] statically indexed -> pure VGPR
//  - float2 weight loads, 8B/lane, coalesced across wave
//  - each x4 LDS broadcast feeds 8 FMAs (was 4)
//  - depth-2 software pipeline over flattened (kp,g): 8 weight loads in flight
//  - OOB rows handled by address clamp: xs pad cols are 0 so product is 0
template <int J, int NKQ>
__device__ __forceinline__ void gemm_cols(const float* xs,
                                          const float* __restrict__ W, int D,
                                          float* outb, int tid)
{
    constexpr int CT  = J / 2;          // column-pair slots
    constexpr int DPT = 256 / NKQ;      // d-rows per kq group per matrix
    constexpr int G   = DPT / 4;        // 4-row groups per matrix
    constexpr int TOT = 3 * G;          // flattened (kp,g) iterations
    const int j  = (tid & (CT - 1)) << 1;
    const int kq = tid / CT;            // wave-uniform
    const int kbase = kq * DPT;

    float acc[19][2];
#pragma unroll
    for (int n = 0; n < 19; ++n) { acc[n][0] = 0.f; acc[n][1] = 0.f; }

    auto loadw = [&](int it, float2* wv) {
        const int kp = it / G;
        const int d0 = kbase + ((it - kp * G) << 2);
#pragma unroll
        for (int r = 0; r < 4; ++r) {
            int d = d0 + r;
            if (d >= D) d = 0;          // xs[:, d>=D] == 0 -> term vanishes
            wv[r] = *(const float2*)(W + (size_t)(3 * d + kp) * J + j);
        }
    };
    auto fmait = [&](int it, const float2* wv) {
        const int kp = it / G;
        const int d0 = kbase + ((it - kp * G) << 2);
        const float* mat = xs + kp * 4864;
#pragma unroll
        for (int n = 0; n < 19; ++n) {
            const float4 x4 = *(const float4*)(mat + (n << 8) + d0);  // broadcast
            acc[n][0] += x4.x * wv[0].x; acc[n][1] += x4.x * wv[0].y;
            acc[n][0] += x4.y * wv[1].x; acc[n][1] += x4.y * wv[1].y;
            acc[n][0] += x4.z * wv[2].x; acc[n][1] += x4.z * wv[2].y;
            acc[n][0] += x4.w * wv[3].x; acc[n][1] += x4.w * wv[3].y;
        }
    };

    float2 wbuf[3][4];
    loadw(0, wbuf[0]);
    loadw(1, wbuf[1]);
#pragma unroll
    for (int it = 0; it < TOT; ++it) {           // full unroll: %3 is compile-time
        if (it + 2 < TOT) loadw(it + 2, wbuf[(it + 2) % 3]);
        fmait(it, wbuf[it % 3]);
    }

#pragma unroll
    for (int n = 0; n < 19; ++n) {
        atomicAdd(outb + n * J + j,     acc[n][0]);
        atomicAdd(outb + n * J + j + 1, acc[n][1]);
    }
}

// ---- projection GEMM: cb(19 x 100, stride 128) += h1(19 x 128) @ Wp(128 x 100)
__device__ __forceinline__ void proj_gemm(const float* h1, const float* __restrict__ Wp,
                                          float* outb, int tid)
{
    const int j = tid & 127;          // 128 col slots, 100 active
    const int kq = tid >> 7;          // 8 K-groups x 16 rows
    const int kbase = kq << 4;
    float acc[19];
#pragma unroll
    for (int n = 0; n < 19; ++n) acc[n] = 0.f;
#pragma unroll 2
    for (int g = 0; g < 4; ++g) {
        const int d0 = kbase + (g << 2);
        const float w0 = (j < 100) ? Wp[(d0 + 0) * 100 + j] : 0.f;
        const float w1 = (j < 100) ? Wp[(d0 + 1) * 100 + j] : 0.f;
        const float w2 = (j < 100) ? Wp[(d0 + 2) * 100 + j] : 0.f;
        const float w3 = (j < 100) ? Wp[(d0 + 3) * 100 + j] : 0.f;
#pragma unroll
        for (int n = 0; n < 19; ++n) {
            const float4 x4 = *(const float4*)(h1 + (n << 7) + d0);  // broadcast
            acc[n] += x4.x * w0;
            acc[n] += x4.y * w1;
            acc[n] += x4.z * w2;
            acc[n] += x4.w * w3;
        }
    }
    if (j < 100) {
#pragma unroll
        for (int n = 0; n < 19; ++n)
            atomicAdd(outb + (n << 7) + j, acc[n]);
    }
}

// ---- one DCGRU cell: h <- u*h + (1-u)*tanh(dconv(x, r*h))
__device__ __forceinline__ void cell(
    int Dx, const float* x, float* h,
    const float* __restrict__ Wg, const float* __restrict__ bg,
    const float* __restrict__ Wc, const float* __restrict__ bc,
    const float* Sm, float* xs, float* m1, float* m2, float* gb, float* cb, int tid)
{
    const int D = Dx + 128;
    // stage xs = [x | h], zero-pad to 256; init gates buffer with bias
    for (int i = tid; i < NV * 256; i += NTHREADS) {
        const int n = i >> 8, d = i & 255;
        float v = 0.f;
        if (d < Dx) v = x[n * Dx + d];
        else if (d < D) v = h[(n << 7) + (d - Dx)];
        xs[i] = v;
        gb[i] = bg[d];
    }
    __syncthreads();
    diffuse(Sm, xs, m1, nullptr, tid);
    __syncthreads();
    diffuse(Sm, m1, m2, xs, tid);
    __syncthreads();
    gemm_cols<256, 8>(xs, Wg, D, gb, tid);
    __syncthreads();
    // sigmoid; write r*h into xs h-part; init cand buffer with bias
    for (int i = tid; i < NV * 256; i += NTHREADS) {
        const int n = i >> 8, j = i & 255;
        const float sg = 1.f / (1.f + __expf(-gb[i]));
        gb[i] = sg;
        if (j < 128) {
            xs[(n << 8) + Dx + j] = sg * h[(n << 7) + j];
            cb[(n << 7) + j] = bc[j];
        }
    }
    __syncthreads();
    diffuse(Sm, xs, m1, nullptr, tid);
    __syncthreads();
    diffuse(Sm, m1, m2, xs, tid);
    __syncthreads();
    gemm_cols<128, 16>(xs, Wc, D, cb, tid);
    __syncthreads();
    // h update: u in gb[:,128:256], c = tanh(cb)
    for (int i = tid; i < NV * 128; i += NTHREADS) {
        const int n = i >> 7, j = i & 127;
        const float u = gb[(n << 8) + 128 + j];
        const float e = __expf(-2.f * cb[i]);
        const float cv = (1.f - e) / (1.f + e);
        h[i] = u * h[i] + (1.f - u) * cv;
    }
    __syncthreads();
}

__global__ __launch_bounds__(NTHREADS) void dcrnn_kernel(
    const float* __restrict__ enc, const float* __restrict__ sup,
    const float* e0Wg, const float* e0bg, const float* e0Wc, const float* e0bc,
    const float* e1Wg, const float* e1bg, const float* e1Wc, const float* e1bc,
    const float* d0Wg, const float* d0bg, const float* d0Wc, const float* d0bc,
    const float* d1Wg, const float* d1bg, const float* d1Wc, const float* d1bc,
    const float* Wp, const float* bp, float* __restrict__ out)
{
    __shared__ __align__(16) float lds[29020];
    float* Sm  = lds;           // 364
    float* h0  = Sm + 364;      // 2432
    float* h1  = h0 + 2432;     // 2432
    float* cur = h1 + 2432;     // 1904
    float* xs  = cur + 1904;    // 4864
    float* m1  = xs + 4864;     // 4864  (contiguous after xs)
    float* m2  = m1 + 4864;     // 4864  (contiguous after m1)
    float* gb  = m2 + 4864;     // 4864
    float* cb  = gb + 4864;     // 2432

    const int tid = threadIdx.x;
    const int b = blockIdx.x;

    for (int i = tid; i < 361; i += NTHREADS) Sm[i] = sup[i];
    for (int i = tid; i < 2432; i += NTHREADS) { h0[i] = 0.f; h1[i] = 0.f; }
    for (int i = tid; i < 1900; i += NTHREADS) cur[i] = 0.f;
    __syncthreads();

    // encoder: two stacked DCGRU layers, interleaved per timestep
    for (int t = 0; t < TT; ++t) {
        const float* xg = enc + ((size_t)b * TT + t) * (NV * 100);
        cell(100, xg, h0, e0Wg, e0bg, e0Wc, e0bc, Sm, xs, m1, m2, gb, cb, tid);
        cell(128, h0, h1, e1Wg, e1bg, e1Wc, e1bc, Sm, xs, m1, m2, gb, cb, tid);
    }
    // decoder: autoregressive, feedback through LDS `cur`
    for (int t = 0; t < TT; ++t) {
        cell(100, cur, h0, d0Wg, d0bg, d0Wc, d0bc, Sm, xs, m1, m2, gb, cb, tid);
        cell(128, h0, h1, d1Wg, d1bg, d1Wc, d1bc, Sm, xs, m1, m2, gb, cb, tid);
        // projection: proj = h1 @ Wp + bp  (into cb, stride 128)
        for (int i = tid; i < NV * 128; i += NTHREADS) {
            const int o = i & 127;
            cb[i] = (o < 100) ? bp[o] : 0.f;
        }
        __syncthreads();
        proj_gemm(h1, Wp, cb, tid);
        __syncthreads();
        float* po = out + ((size_t)b * TT + t) * (NV * 100);
        for (int i = tid; i < NV * 100; i += NTHREADS) {
            const int n = i / 100;
            const int o = i - n * 100;
            const float v = cb[(n << 7) + o];
            po[i] = v;
            cur[i] = v;
        }
        __syncthreads();
    }
}

extern "C" void kernel_launch(void* const* d_in, const int* in_sizes, int n_in,
                              void* d_out, int out_size, void* d_ws, size_t ws_size,
                              hipStream_t stream)
{
    const float* enc  = (const float*)d_in[0];
    // d_in[1] = decoder_inputs: values unused by the reference (autoregressive feedback)
    const float* sup  = (const float*)d_in[2];
    const float* e0Wg = (const float*)d_in[3];
    const float* e0bg = (const float*)d_in[4];
    const float* e0Wc = (const float*)d_in[5];
    const float* e0bc = (const float*)d_in[6];
    const float* e1Wg = (const float*)d_in[7];
    const float* e1bg = (const float*)d_in[8];
    const float* e1Wc = (const float*)d_in[9];
    const float* e1bc = (const float*)d_in[10];
    const float* d0Wg = (const float*)d_in[11];
    const float* d0bg = (const float*)d_in[12];
    const float* d0Wc = (const float*)d_in[13];
    const float* d0bc = (const float*)d_in[14];
    const float* d1Wg = (const float*)d_in[15];
    const float* d1bg = (const float*)d_in[16];
    const float* d1Wc = (const float*)d_in[17];
    const float* d1bc = (const float*)d_in[18];
    const float* Wp   = (const float*)d_in[19];
    const float* bp   = (const float*)d_in[20];

    dcrnn_kernel<<<dim3(NB), dim3(NTHREADS), 0, stream>>>(
        enc, sup,
        e0Wg, e0bg, e0Wc, e0bc, e1Wg, e1bg, e1Wc, e1bc,
        d0Wg, d0bg, d0Wc, d0bc, d1Wg, d1bg, d1Wc, d1bc,
        Wp, bp, (float*)d_out);
}

// Round 3
// 26944.583 us; speedup vs baseline: 1.8027x; 1.8027x over previous
//
#include <hip/hip_runtime.h>

#define NTHREADS 1024
#define NB 256
#define TT 64
#define NV 19

typedef unsigned short ush;
typedef unsigned int uint32;
typedef __attribute__((ext_vector_type(8))) short short8;
typedef __attribute__((ext_vector_type(4))) float f32x4;

// fragment-ordered weight array sizes (ushorts): [24 ktiles][NT ntiles][64 lanes][8 elems]
#define SZA 196608   // J=256 (NT=16)
#define SZB 98304    // J=128 (NT=8)

// ---------- numeric helpers: exact hi/lo bf16 split (truncation; residual exact in fp32)
__device__ __forceinline__ ush f2hi(float x) { return (ush)(__float_as_uint(x) >> 16); }
__device__ __forceinline__ float hi2f(ush h) { return __uint_as_float((uint32)h << 16); }
__device__ __forceinline__ void split2(float x, ush& h, ush& l) {
    h = f2hi(x);
    l = f2hi(x - hi2f(h));
}

// ---------- LDS swizzles (kill column-read bank conflicts; XOR low-3 bits of 16B unit idx)
// xs/m1 fp32 arrays: row stride 64 float4-units
__device__ __forceinline__ int swzf4(int row, int c4) { return ((row << 6) | c4) ^ (row & 7); }
// Ah/Al bf16 arrays: row stride 96 units of 8 ushorts (768 k-slots)
__device__ __forceinline__ int swzu(int row, int u) { return row * 96 + (u ^ (row & 7)); }

// ---------- prep kernel: re-tile + hi/lo-split all 8 diffusion weight matrices into ws
// k-order: k = kp*256 + d  (block order, NOT the torch 3d+kp interleave)
// per matrix: h-array then l-array; layer-pair stride 2*(SZA+SZB)
__global__ void prep_kernel(const float* e0Wg, const float* e0Wc,
                            const float* e1Wg, const float* e1Wc,
                            const float* d0Wg, const float* d0Wc,
                            const float* d1Wg, const float* d1Wc,
                            ush* __restrict__ ws)
{
    const float* srcs[8] = {e0Wg, e0Wc, e1Wg, e1Wc, d0Wg, d0Wc, d1Wg, d1Wc};
    const long tot = 4L * SZA + 4L * SZB;
    for (long p = (long)blockIdx.x * blockDim.x + threadIdx.x; p < tot;
         p += (long)gridDim.x * blockDim.x) {
        long rem = p;
        long base = 0;
        int i = 0;
        for (; i < 8; ++i) {
            const long s = (i & 1) ? SZB : SZA;
            if (rem < s) break;
            rem -= s;
            base += 2 * s;
        }
        const long s = (i & 1) ? SZB : SZA;
        const int J = (i & 1) ? 128 : 256;
        const int NT = J >> 4;
        const int Dd = ((i >> 1) & 1) ? 256 : 228;   // e0,d0: 228; e1,d1: 256
        const int e = (int)(rem & 7);
        const int lane = (int)((rem >> 3) & 63);
        const long blk = rem >> 9;                   // kt*NT + nt
        const int nt = (int)(blk % NT);
        const int kt = (int)(blk / NT);
        const int k = kt * 32 + (lane >> 4) * 8 + e;
        const int j = nt * 16 + (lane & 15);
        const int kp = k >> 8, d = k & 255;
        float v = 0.f;
        if (d < Dd) v = srcs[i][(long)(3 * d + kp) * J + j];
        ush hh, ll;
        split2(v, hh, ll);
        ws[base + rem] = hh;
        ws[base + s + rem] = ll;
    }
}

// ---------- diffusion: dst[n][:] = S @ src (or 2*(S@src) - sub); writes fp32 (optional)
// and bf16 hi/lo split into Ah/Al at k-offset kofs. 16 waves x rows {w, w+16}.
__device__ __forceinline__ void diffuse(const float* Sm, const float* src, float* dstF,
                                        const float* sub, ush* Ah, ush* Al,
                                        int kofs, int tid)
{
    const int w = tid >> 6;
    const int c = tid & 63;            // float4 column index
    const int n0 = w, n1 = w + 16;
    float4 a0 = {0.f, 0.f, 0.f, 0.f};
    float4 a1 = {0.f, 0.f, 0.f, 0.f};
#pragma unroll 1
    for (int m = 0; m < 19; ++m) {
        const float4 x4 = ((const float4*)src)[swzf4(m, c)];
        const float s0 = Sm[n0 * 19 + m];
        a0.x += s0 * x4.x; a0.y += s0 * x4.y; a0.z += s0 * x4.z; a0.w += s0 * x4.w;
        if (n1 < 19) {
            const float s1 = Sm[n1 * 19 + m];
            a1.x += s1 * x4.x; a1.y += s1 * x4.y; a1.z += s1 * x4.z; a1.w += s1 * x4.w;
        }
    }
    if (sub) {
        const float4 u0 = ((const float4*)sub)[swzf4(n0, c)];
        a0.x = 2.f * a0.x - u0.x; a0.y = 2.f * a0.y - u0.y;
        a0.z = 2.f * a0.z - u0.z; a0.w = 2.f * a0.w - u0.w;
        if (n1 < 19) {
            const float4 u1 = ((const float4*)sub)[swzf4(n1, c)];
            a1.x = 2.f * a1.x - u1.x; a1.y = 2.f * a1.y - u1.y;
            a1.z = 2.f * a1.z - u1.z; a1.w = 2.f * a1.w - u1.w;
        }
    }
    const int ub = kofs >> 3;
    const int half = (c & 1) << 2;
    {
        if (dstF) ((float4*)dstF)[swzf4(n0, c)] = a0;
        const int u = swzu(n0, ub + (c >> 1));
        ush h0_, l0_, h1_, l1_, h2_, l2_, h3_, l3_;
        split2(a0.x, h0_, l0_); split2(a0.y, h1_, l1_);
        split2(a0.z, h2_, l2_); split2(a0.w, h3_, l3_);
        *(ushort4*)(Ah + u * 8 + half) = make_ushort4(h0_, h1_, h2_, h3_);
        *(ushort4*)(Al + u * 8 + half) = make_ushort4(l0_, l1_, l2_, l3_);
    }
    if (n1 < 19) {
        if (dstF) ((float4*)dstF)[swzf4(n1, c)] = a1;
        const int u = swzu(n1, ub + (c >> 1));
        ush h0_, l0_, h1_, l1_, h2_, l2_, h3_, l3_;
        split2(a1.x, h0_, l0_); split2(a1.y, h1_, l1_);
        split2(a1.z, h2_, l2_); split2(a1.w, h3_, l3_);
        *(ushort4*)(Ah + u * 8 + half) = make_ushort4(h0_, h1_, h2_, h3_);
        *(ushort4*)(Al + u * 8 + half) = make_ushort4(l0_, l1_, l2_, l3_);
    }
}

// ---------- stage xs = [x | h | 0pad] (fp32 swizzled + bf16 split at k in [0,256))
__device__ __forceinline__ void stage(int Dx, const float* x, const float* h,
                                      float* xs, ush* Ah, ush* Al, int tid)
{
    for (int i = tid; i < NV * 256; i += NTHREADS) {
        const int n = i >> 8, d = i & 255;
        float v = 0.f;
        if (d < Dx) v = x[n * Dx + d];
        else if (d < Dx + 128) v = h[(n << 7) + d - Dx];
        xs[swzf4(n, d >> 2) * 4 + (d & 3)] = v;
        ush hh, ll;
        split2(v, hh, ll);
        const int u = swzu(n, d >> 3);
        Ah[u * 8 + (d & 7)] = hh;
        Al[u * 8 + (d & 7)] = ll;
    }
}

// ---------- MFMA GEMM: acc[4] += X(19x768,split) @ W'(768xJ,split), J = NT*16
// NWAVE active waves, 4 output tiles each (2 mtiles x NT ntiles total).
// 3-MFMA bf16 split: AhBh + AlBh + AhBl (AlBl dropped, ~2^-32).
template <int NT, int NWAVE>
__device__ __forceinline__ void mfma_gemm(const ush* Ah, const ush* Al,
                                          const ush* __restrict__ Bh,
                                          const ush* __restrict__ Bl,
                                          f32x4* acc, int tid)
{
    if ((tid >> 6) >= NWAVE) return;
    const int w = tid >> 6, l = tid & 63;
    const int mt = w / (NWAVE / 2);
    const int nt0 = (w % (NWAVE / 2)) * 4;
    const int rl = l & 15, lg = l >> 4;
    const int r = mt * 16 + rl;
    const bool rok = (r < 19);
    const int rc = rok ? r : 0;
#pragma unroll 1
    for (int kt = 0; kt < 24; ++kt) {
        // B loads first (global, longest latency)
        short8 bh0, bl0, bh1, bl1, bh2, bl2, bh3, bl3;
        {
            const int o0 = ((kt * NT + nt0 + 0) * 64 + l) * 8;
            const int o1 = ((kt * NT + nt0 + 1) * 64 + l) * 8;
            const int o2 = ((kt * NT + nt0 + 2) * 64 + l) * 8;
            const int o3 = ((kt * NT + nt0 + 3) * 64 + l) * 8;
            bh0 = *(const short8*)(Bh + o0); bl0 = *(const short8*)(Bl + o0);
            bh1 = *(const short8*)(Bh + o1); bl1 = *(const short8*)(Bl + o1);
            bh2 = *(const short8*)(Bh + o2); bl2 = *(const short8*)(Bl + o2);
            bh3 = *(const short8*)(Bh + o3); bl3 = *(const short8*)(Bl + o3);
        }
        // A frags (LDS, swizzled)
        const int au = swzu(rc, kt * 4 + lg) * 8;
        short8 ah = *(const short8*)(Ah + au);
        short8 al = *(const short8*)(Al + au);
        if (!rok) { ah = 0; al = 0; }
        acc[0] = __builtin_amdgcn_mfma_f32_16x16x32_bf16(ah, bh0, acc[0], 0, 0, 0);
        acc[1] = __builtin_amdgcn_mfma_f32_16x16x32_bf16(ah, bh1, acc[1], 0, 0, 0);
        acc[2] = __builtin_amdgcn_mfma_f32_16x16x32_bf16(ah, bh2, acc[2], 0, 0, 0);
        acc[3] = __builtin_amdgcn_mfma_f32_16x16x32_bf16(ah, bh3, acc[3], 0, 0, 0);
        acc[0] = __builtin_amdgcn_mfma_f32_16x16x32_bf16(al, bh0, acc[0], 0, 0, 0);
        acc[1] = __builtin_amdgcn_mfma_f32_16x16x32_bf16(al, bh1, acc[1], 0, 0, 0);
        acc[2] = __builtin_amdgcn_mfma_f32_16x16x32_bf16(al, bh2, acc[2], 0, 0, 0);
        acc[3] = __builtin_amdgcn_mfma_f32_16x16x32_bf16(al, bh3, acc[3], 0, 0, 0);
        acc[0] = __builtin_amdgcn_mfma_f32_16x16x32_bf16(ah, bl0, acc[0], 0, 0, 0);
        acc[1] = __builtin_amdgcn_mfma_f32_16x16x32_bf16(ah, bl1, acc[1], 0, 0, 0);
        acc[2] = __builtin_amdgcn_mfma_f32_16x16x32_bf16(ah, bl2, acc[2], 0, 0, 0);
        acc[3] = __builtin_amdgcn_mfma_f32_16x16x32_bf16(ah, bl3, acc[3], 0, 0, 0);
    }
}

// ---------- gates epilogue: sigmoid; r*h -> xs h-part (+split); u -> ub
// C/D layout (m89-verified): col = lane&15, row = (lane>>4)*4 + reg
__device__ __forceinline__ void epi_gates(const f32x4* acc, const float* __restrict__ bg,
                                          float* xs, ush* Ah, ush* Al,
                                          const float* h, float* ub, int Dx, int tid)
{
    if ((tid >> 6) >= 8) return;
    const int w = tid >> 6, l = tid & 63;
    const int mt = w >> 2, nt0 = (w & 3) << 2;
    const int rl = l & 15, lg = l >> 4;
#pragma unroll
    for (int t = 0; t < 4; ++t) {
        const int J = (nt0 + t) * 16 + rl;
        const float bb = bg[J];
#pragma unroll
        for (int q = 0; q < 4; ++q) {
            const int R = mt * 16 + lg * 4 + q;
            if (R < 19) {
                const float z = acc[t][q] + bb;
                const float sg = 1.f / (1.f + __expf(-z));
                if (J < 128) {
                    const float rh = sg * h[(R << 7) + J];
                    const int d = Dx + J;
                    xs[swzf4(R, d >> 2) * 4 + (d & 3)] = rh;
                    ush hh, ll;
                    split2(rh, hh, ll);
                    const int u = swzu(R, d >> 3);
                    Ah[u * 8 + (d & 7)] = hh;
                    Al[u * 8 + (d & 7)] = ll;
                } else {
                    ub[(R << 7) + J - 128] = sg;
                }
            }
        }
    }
}

// ---------- cand epilogue: c = tanh; h <- u*h + (1-u)*c
__device__ __forceinline__ void epi_cand(const f32x4* acc, const float* __restrict__ bc,
                                         const float* ub, float* h, int tid)
{
    if ((tid >> 6) >= 4) return;
    const int w = tid >> 6, l = tid & 63;
    const int mt = w >> 1, nt0 = (w & 1) << 2;
    const int rl = l & 15, lg = l >> 4;
#pragma unroll
    for (int t = 0; t < 4; ++t) {
        const int J = (nt0 + t) * 16 + rl;
        const float bb = bc[J];
#pragma unroll
        for (int q = 0; q < 4; ++q) {
            const int R = mt * 16 + lg * 4 + q;
            if (R < 19) {
                const float z = acc[t][q] + bb;
                const float e = __expf(-2.f * z);
                const float c = (1.f - e) / (1.f + e);
                const float u = ub[(R << 7) + J];
                h[(R << 7) + J] = u * h[(R << 7) + J] + (1.f - u) * c;
            }
        }
    }
}

// ---------- one DCGRU cell
__device__ __forceinline__ void cell(
    int Dx, const float* x, float* h,
    const ush* Bgh, const ush* Bgl, const ush* Bch, const ush* Bcl,
    const float* __restrict__ bg, const float* __restrict__ bc,
    const float* Sm, float* xs, float* m1, ush* Ah, ush* Al, float* ub, int tid)
{
    stage(Dx, x, h, xs, Ah, Al, tid);
    __syncthreads();
    diffuse(Sm, xs, m1, nullptr, Ah, Al, 256, tid);
    __syncthreads();
    diffuse(Sm, m1, nullptr, xs, Ah, Al, 512, tid);   // m2: split only, no fp32 copy
    __syncthreads();
    {
        f32x4 acc[4];
#pragma unroll
        for (int t = 0; t < 4; ++t) acc[t] = 0.f;
        mfma_gemm<16, 8>(Ah, Al, Bgh, Bgl, acc, tid);
        __syncthreads();                               // K-loop reads done before epi writes
        epi_gates(acc, bg, xs, Ah, Al, h, ub, Dx, tid);
    }
    __syncthreads();
    diffuse(Sm, xs, m1, nullptr, Ah, Al, 256, tid);
    __syncthreads();
    diffuse(Sm, m1, nullptr, xs, Ah, Al, 512, tid);
    __syncthreads();
    {
        f32x4 acc[4];
#pragma unroll
        for (int t = 0; t < 4; ++t) acc[t] = 0.f;
        mfma_gemm<8, 4>(Ah, Al, Bch, Bcl, acc, tid);
        __syncthreads();
        epi_cand(acc, bc, ub, h, tid);
    }
    __syncthreads();
}

// ---------- projection GEMM (unchanged R1 path): ub(19x100,s128) += h1 @ Wp
__device__ __forceinline__ void proj_gemm(const float* h1, const float* __restrict__ Wp,
                                          float* outb, int tid)
{
    const int j = tid & 127;
    const int kq = tid >> 7;
    const int kbase = kq << 4;
    float acc[19];
#pragma unroll
    for (int n = 0; n < 19; ++n) acc[n] = 0.f;
#pragma unroll 2
    for (int g = 0; g < 4; ++g) {
        const int d0 = kbase + (g << 2);
        const float w0 = (j < 100) ? Wp[(d0 + 0) * 100 + j] : 0.f;
        const float w1 = (j < 100) ? Wp[(d0 + 1) * 100 + j] : 0.f;
        const float w2 = (j < 100) ? Wp[(d0 + 2) * 100 + j] : 0.f;
        const float w3 = (j < 100) ? Wp[(d0 + 3) * 100 + j] : 0.f;
#pragma unroll
        for (int n = 0; n < 19; ++n) {
            const float4 x4 = *(const float4*)(h1 + (n << 7) + d0);
            acc[n] += x4.x * w0;
            acc[n] += x4.y * w1;
            acc[n] += x4.z * w2;
            acc[n] += x4.w * w3;
        }
    }
    if (j < 100) {
#pragma unroll
        for (int n = 0; n < 19; ++n)
            atomicAdd(outb + (n << 7) + j, acc[n]);
    }
}

// LDS (floats): Sm 364 | h0 2432 | h1 2432 | cur 1904 | xs 4864 | m1 4864 | ub 2432
//               | Ah 7296 | Al 7296  = 33884 floats = 135,536 B (<= 160 KiB)
__global__ __launch_bounds__(NTHREADS) void dcrnn_kernel(
    const float* __restrict__ enc, const float* __restrict__ sup,
    const float* e0bg, const float* e0bc, const float* e1bg, const float* e1bc,
    const float* d0bg, const float* d0bc, const float* d1bg, const float* d1bc,
    const float* Wp, const float* bp, const ush* __restrict__ ws,
    float* __restrict__ out)
{
    __shared__ __align__(16) float lds[33884];
    float* Sm  = lds;            // 364
    float* h0  = Sm + 364;       // 2432
    float* h1  = h0 + 2432;      // 2432
    float* cur = h1 + 2432;      // 1904
    float* xs  = cur + 1904;     // 4864 (swizzled fp32)
    float* m1  = xs + 4864;      // 4864 (swizzled fp32)
    float* ub  = m1 + 4864;      // 2432 (u-gate / proj buffer)
    ush*   Ah  = (ush*)(ub + 2432);   // 14592 ushorts
    ush*   Al  = Ah + 14592;          // 14592 ushorts

    const int tid = threadIdx.x;
    const int b = blockIdx.x;

    // fragment-ordered weight bases in ws (ushort offsets)
    const long LP = 2L * (SZA + SZB);  // layer-pair stride
    const ush* e0Bgh = ws + 0 * LP;          const ush* e0Bgl = e0Bgh + SZA;
    const ush* e0Bch = e0Bgh + 2 * SZA;      const ush* e0Bcl = e0Bch + SZB;
    const ush* e1Bgh = ws + 1 * LP;          const ush* e1Bgl = e1Bgh + SZA;
    const ush* e1Bch = e1Bgh + 2 * SZA;      const ush* e1Bcl = e1Bch + SZB;
    const ush* d0Bgh = ws + 2 * LP;          const ush* d0Bgl = d0Bgh + SZA;
    const ush* d0Bch = d0Bgh + 2 * SZA;      const ush* d0Bcl = d0Bch + SZB;
    const ush* d1Bgh = ws + 3 * LP;          const ush* d1Bgl = d1Bgh + SZA;
    const ush* d1Bch = d1Bgh + 2 * SZA;      const ush* d1Bcl = d1Bch + SZB;

    for (int i = tid; i < 361; i += NTHREADS) Sm[i] = sup[i];
    for (int i = tid; i < 2432; i += NTHREADS) { h0[i] = 0.f; h1[i] = 0.f; }
    for (int i = tid; i < 1900; i += NTHREADS) cur[i] = 0.f;
    __syncthreads();

    // encoder
    for (int t = 0; t < TT; ++t) {
        const float* xg = enc + ((size_t)b * TT + t) * (NV * 100);
        cell(100, xg, h0, e0Bgh, e0Bgl, e0Bch, e0Bcl, e0bg, e0bc,
             Sm, xs, m1, Ah, Al, ub, tid);
        cell(128, h0, h1, e1Bgh, e1Bgl, e1Bch, e1Bcl, e1bg, e1bc,
             Sm, xs, m1, Ah, Al, ub, tid);
    }
    // decoder (autoregressive)
    for (int t = 0; t < TT; ++t) {
        cell(100, cur, h0, d0Bgh, d0Bgl, d0Bch, d0Bcl, d0bg, d0bc,
             Sm, xs, m1, Ah, Al, ub, tid);
        cell(128, h0, h1, d1Bgh, d1Bgl, d1Bch, d1Bcl, d1bg, d1bc,
             Sm, xs, m1, Ah, Al, ub, tid);
        // projection into ub
        for (int i = tid; i < NV * 128; i += NTHREADS) {
            const int o = i & 127;
            ub[i] = (o < 100) ? bp[o] : 0.f;
        }
        __syncthreads();
        proj_gemm(h1, Wp, ub, tid);
        __syncthreads();
        float* po = out + ((size_t)b * TT + t) * (NV * 100);
        for (int i = tid; i < NV * 100; i += NTHREADS) {
            const int n = i / 100;
            const int o = i - n * 100;
            const float v = ub[(n << 7) + o];
            po[i] = v;
            cur[i] = v;
        }
        __syncthreads();
    }
}

extern "C" void kernel_launch(void* const* d_in, const int* in_sizes, int n_in,
                              void* d_out, int out_size, void* d_ws, size_t ws_size,
                              hipStream_t stream)
{
    const float* enc  = (const float*)d_in[0];
    // d_in[1] = decoder_inputs: unused by reference (autoregressive feedback)
    const float* sup  = (const float*)d_in[2];
    const float* e0Wg = (const float*)d_in[3];
    const float* e0bg = (const float*)d_in[4];
    const float* e0Wc = (const float*)d_in[5];
    const float* e0bc = (const float*)d_in[6];
    const float* e1Wg = (const float*)d_in[7];
    const float* e1bg = (const float*)d_in[8];
    const float* e1Wc = (const float*)d_in[9];
    const float* e1bc = (const float*)d_in[10];
    const float* d0Wg = (const float*)d_in[11];
    const float* d0bg = (const float*)d_in[12];
    const float* d0Wc = (const float*)d_in[13];
    const float* d0bc = (const float*)d_in[14];
    const float* d1Wg = (const float*)d_in[15];
    const float* d1bg = (const float*)d_in[16];
    const float* d1Wc = (const float*)d_in[17];
    const float* d1bc = (const float*)d_in[18];
    const float* Wp   = (const float*)d_in[19];
    const float* bp   = (const float*)d_in[20];

    ush* ws = (ush*)d_ws;   // needs 4*(2*SZA+2*SZB)*2B = 4.52 MB

    prep_kernel<<<dim3(512), dim3(256), 0, stream>>>(
        e0Wg, e0Wc, e1Wg, e1Wc, d0Wg, d0Wc, d1Wg, d1Wc, ws);

    dcrnn_kernel<<<dim3(NB), dim3(NTHREADS), 0, stream>>>(
        enc, sup,
        e0bg, e0bc, e1bg, e1bc, d0bg, d0bc, d1bg, d1bc,
        Wp, bp, ws, (float*)d_out);
}